// Round 7
// baseline (155.788 us; speedup 1.0000x reference)
//
#include <hip/hip_runtime.h>
#include <stdint.h>

#define N      8192
#define KDIM   256
#define BM     128
#define TILES  (N / BM)                    // 64
#define NPAIRS (TILES * (TILES + 1) / 2)   // 2080
#define GRID   1024                        // 4 persistent blocks per CU
#define MARGIN 0.5f
#define SCALE1 0x7f7f7f7f                  // E8M0 1.0 in every byte

typedef float f32x4 __attribute__((ext_vector_type(4)));
typedef int   i32x4 __attribute__((ext_vector_type(4)));
typedef int   i32x8 __attribute__((ext_vector_type(8)));

__device__ __forceinline__ void async_copy16(const void* g, void* l) {
    __builtin_amdgcn_global_load_lds(
        (__attribute__((address_space(1))) void*)(g),
        (__attribute__((address_space(3))) void*)(l),
        16, 0, 0);
}

#if !__has_builtin(__builtin_amdgcn_cvt_pk_fp8_f32)
__device__ __forceinline__ uint32_t f2e4m3(float f) {
    uint32_t u = __float_as_uint(f);
    uint32_t s = (u >> 24) & 0x80u;
    uint32_t au = u & 0x7fffffffu;
    if (au == 0) return s;
    int32_t  exp = (int32_t)(au >> 23) - 127;
    uint32_t man = (au & 0x7fffffu) | 0x800000u;
    uint32_t code;
    if (exp >= -6) {
        code = (uint32_t)((exp + 7) << 3) | ((man >> 20) & 7u);
        uint32_t rem = man & 0xFFFFFu;
        if (rem > 0x80000u || (rem == 0x80000u && (code & 1u))) code++;
    } else {
        int shift = 14 - exp;
        if (shift > 24) return s;
        code = man >> shift;
        uint32_t rem = man & ((1u << shift) - 1u);
        uint32_t h = 1u << (shift - 1);
        if (rem > h || (rem == h && (code & 1u))) code++;
    }
    return s | code;
}
__device__ __forceinline__ uint32_t pack_fp8x4(float4 v) {
    return f2e4m3(v.x) | (f2e4m3(v.y) << 8) | (f2e4m3(v.z) << 16) |
           (f2e4m3(v.w) << 24);
}
#else
__device__ __forceinline__ uint32_t pack_fp8x4(float4 v) {
    int pk = __builtin_amdgcn_cvt_pk_fp8_f32(v.x, v.y, 0, false);
    pk = __builtin_amdgcn_cvt_pk_fp8_f32(v.z, v.w, pk, true);
    return (uint32_t)pk;
}
#endif

// ---------------------------------------------------------------------------
// Prepass: fp32 -> fp8 e4m3, row-major 256 B/row, 16 B granules XOR-swizzled
// by (row&7) within each 128 B half. Exact fp32 row norms.
// ---------------------------------------------------------------------------
__global__ __launch_bounds__(256) void prep_kernel(
        const float* __restrict__ X, uint8_t* __restrict__ Xq,
        float* __restrict__ sq) {
    int row  = blockIdx.x * 4 + (threadIdx.x >> 6);
    int lane = threadIdx.x & 63;

    float4 v = *((const float4*)(X + (size_t)row * KDIM) + lane);
    float ss = v.x * v.x + v.y * v.y + v.z * v.z + v.w * v.w;
    uint32_t pk = pack_fp8x4(v);

    int h   = lane >> 5;
    int g   = (lane >> 2) & 7;
    int pos = g ^ (row & 7);
    *(uint32_t*)(Xq + (size_t)row * 256 + h * 128 + pos * 16 + (lane & 3) * 4) = pk;

    #pragma unroll
    for (int o = 32; o > 0; o >>= 1) ss += __shfl_down(ss, o, 64);
    if (lane == 0) sq[row] = ss;
}

// ---------------------------------------------------------------------------
// Main: 1024 PERSISTENT blocks (4/CU), each looping over 2-3 tile-pairs.
// Per pair: 2 LDS-staged K-halves, MX-scaled fp8 MFMA. Cross-pair software
// pipeline: next pair's stage0 + meta ds-write are issued after the epilogue
// metadata has been pulled into registers, so the epilogue is PURE VALU and
// covers the stage drain. Meta is double-buffered (2.5 KB).
// ---------------------------------------------------------------------------
__global__ __launch_bounds__(256, 4) void loss_kernel(
        const uint8_t* __restrict__ Xq, const float* __restrict__ sq,
        const int* __restrict__ tgt, float* __restrict__ partials) {
    __shared__ __align__(16) uint8_t As[BM * 128];   // 16 KB (one K-half)
    __shared__ __align__(16) uint8_t Bs[BM * 128];   // 16 KB
    __shared__ __align__(16) float sqm[2][2][BM];    // [buf][a|b][row]
    __shared__ __align__(16) int   tm [2][2][BM];
    __shared__ float wsum[4];

    const int tid  = threadIdx.x;
    const int wave = tid >> 6;
    const int lane = tid & 63;

    const int frow  = lane & 15;
    const int fquad = lane >> 4;
    const int wm  = (wave >> 1) * 64;
    const int wn  = (wave & 1) * 64;
    const int key = frow & 7;
    const int off0 = ((fquad * 2 + 0) ^ key) * 16;
    const int off1 = ((fquad * 2 + 1) ^ key) * 16;
    const uint8_t* aBp = As + (wm + frow) * 128;
    const uint8_t* bBp = Bs + (wn + frow) * 128;

    const int lrow = lane >> 3;
    const int lb   = (lane & 7) * 16;
    uint8_t* lA = As + wave * 32 * 128;
    uint8_t* lB = Bs + wave * 32 * 128;

    auto decode = [&](int p, int& bi, int& bj) {
        float tf = 2.0f * TILES + 1.0f;
        int b = (int)((tf - sqrtf(tf * tf - 8.0f * (float)p)) * 0.5f);
        if (b < 0) b = 0;
        while (b > 0 && (b * TILES - b * (b - 1) / 2) > p) --b;
        while (((b + 1) * TILES - (b + 1) * b / 2) <= p) ++b;
        bi = b;
        bj = b + (p - (b * TILES - b * (b - 1) / 2));
    };
    auto stage = [&](int bi, int bj, int h) {
        const uint8_t* gA =
            Xq + ((size_t)bi * BM + wave * 32 + lrow) * 256 + lb + h * 128;
        const uint8_t* gB =
            Xq + ((size_t)bj * BM + wave * 32 + lrow) * 256 + lb + h * 128;
        #pragma unroll
        for (int q = 0; q < 4; ++q) {
            async_copy16(gA + q * 8 * 256, lA + q * 1024);
            async_copy16(gB + q * 8 * 256, lB + q * 1024);
        }
    };
    auto meta_fetch = [&](int bi, int bj, float& mv, int& ti) {
        int r = tid & 127;
        int base = ((tid < 128) ? bi : bj) * BM + r;
        mv = sq[base];
        ti = tgt[base];
    };
    auto meta_store = [&](int buf, float mv, int ti) {
        int r = tid & 127;
        int ab = (tid < 128) ? 0 : 1;
        sqm[buf][ab][r] = mv;
        tm [buf][ab][r] = ti;
    };

    // ---- prologue: pair 0 ----
    int p = blockIdx.x;
    int bi, bj;
    decode(p, bi, bj);
    {
        float mv; int ti;
        meta_fetch(bi, bj, mv, ti);
        stage(bi, bj, 0);
        meta_store(0, mv, ti);
    }
    __syncthreads();                       // A: stage0 + meta(0) ready

    int   buf   = 0;
    float total = 0.0f;

    while (true) {
        f32x4 acc[4][4];
        #pragma unroll
        for (int im = 0; im < 4; ++im)
            #pragma unroll
            for (int in = 0; in < 4; ++in)
                acc[im][in] = (f32x4){0.f, 0.f, 0.f, 0.f};

        #define COMPUTE()                                                      \
            do {                                                               \
                i32x8 a8[4];                                                   \
                _Pragma("unroll")                                              \
                for (int im = 0; im < 4; ++im) {                               \
                    i32x4 al = *(const i32x4*)(aBp + im * 16 * 128 + off0);    \
                    i32x4 ah = *(const i32x4*)(aBp + im * 16 * 128 + off1);    \
                    a8[im] = __builtin_shufflevector(al, ah,                   \
                                                     0, 1, 2, 3, 4, 5, 6, 7); \
                }                                                              \
                _Pragma("unroll")                                              \
                for (int in = 0; in < 4; ++in) {                               \
                    i32x4 bl = *(const i32x4*)(bBp + in * 16 * 128 + off0);    \
                    i32x4 bh = *(const i32x4*)(bBp + in * 16 * 128 + off1);    \
                    i32x8 b8 = __builtin_shufflevector(bl, bh,                 \
                                                       0, 1, 2, 3, 4, 5, 6, 7);\
                    _Pragma("unroll")                                          \
                    for (int im = 0; im < 4; ++im)                             \
                        acc[im][in] =                                          \
                            __builtin_amdgcn_mfma_scale_f32_16x16x128_f8f6f4(  \
                                a8[im], b8, acc[im][in], 0, 0,                 \
                                0, SCALE1, 0, SCALE1);                         \
                }                                                              \
            } while (0)

        COMPUTE();                         // K-half 0
        __syncthreads();                   // B: h0 reads done
        stage(bi, bj, 1);

        // prefetch next pair's meta while h1 stages/computes
        int  pn   = p + GRID;
        bool more = (pn < NPAIRS);
        int  bi2 = bi, bj2 = bj;
        float mv = 0.0f; int ti = 0;
        if (more) {
            decode(pn, bi2, bj2);
            meta_fetch(bi2, bj2, mv, ti);
        }
        __syncthreads();                   // C: stage1 drained
        COMPUTE();                         // K-half 1
        __syncthreads();                   // D: h1 reads done
        #undef COMPUTE

        // pull epilogue metadata into registers BEFORE issuing next stage
        f32x4 sqa4[4]; i32x4 ta4[4];
        float sqb_l[4]; int tb_l[4];
        #pragma unroll
        for (int im = 0; im < 4; ++im) {
            sqa4[im] = *(const f32x4*)&sqm[buf][0][wm + im * 16 + fquad * 4];
            ta4[im]  = *(const i32x4*)&tm [buf][0][wm + im * 16 + fquad * 4];
        }
        #pragma unroll
        for (int in = 0; in < 4; ++in) {
            sqb_l[in] = sqm[buf][1][wn + in * 16 + frow];
            tb_l[in]  = tm [buf][1][wn + in * 16 + frow];
        }

        if (more) {
            meta_store(buf ^ 1, mv, ti);   // ds_write before stage issue
            stage(bi2, bj2, 0);            // drain covered by epilogue below
        }

        // ---- PURE-VALU epilogue ----
        float ls = 0.0f;
        if (bi != bj) {
            #pragma unroll
            for (int im = 0; im < 4; ++im)
                #pragma unroll
                for (int in = 0; in < 4; ++in)
                    #pragma unroll
                    for (int r = 0; r < 4; ++r) {
                        float d = fmaf(-2.0f, acc[im][in][r],
                                       sqa4[im][r] + sqb_l[in]);
                        ls += (ta4[im][r] == tb_l[in])
                                  ? d : fmaxf(MARGIN - d, 0.0f);
                    }
            total += 2.0f * ls;
        } else {
            #pragma unroll
            for (int im = 0; im < 4; ++im)
                #pragma unroll
                for (int in = 0; in < 4; ++in)
                    #pragma unroll
                    for (int r = 0; r < 4; ++r) {
                        int rl = wm + im * 16 + fquad * 4 + r;
                        int cl = wn + in * 16 + frow;
                        float d = fmaf(-2.0f, acc[im][in][r],
                                       sqa4[im][r] + sqb_l[in]);
                        float c = (ta4[im][r] == tb_l[in])
                                      ? d : fmaxf(MARGIN - d, 0.0f);
                        float w = (rl < cl) ? 2.0f : ((rl == cl) ? 1.0f : 0.0f);
                        ls += w * c;
                    }
            total += ls;
        }

        if (!more) break;
        p = pn; bi = bi2; bj = bj2; buf ^= 1;
        __syncthreads();                   // A(next): stage0+meta drained
    }

    // ---- per-block reduction ----
    #pragma unroll
    for (int o = 32; o > 0; o >>= 1) total += __shfl_down(total, o, 64);
    if (lane == 0) wsum[wave] = total;
    __syncthreads();
    if (tid == 0) partials[blockIdx.x] = wsum[0] + wsum[1] + wsum[2] + wsum[3];
}

// ---------------------------------------------------------------------------
// Final deterministic reduce of GRID partials -> scaled scalar.
// ---------------------------------------------------------------------------
__global__ __launch_bounds__(256) void reduce_kernel(
        const float* __restrict__ partials, float* __restrict__ out,
        int n, float scale) {
    float s = 0.0f;
    for (int i = threadIdx.x; i < n; i += 256) s += partials[i];
    __shared__ float w[4];
    #pragma unroll
    for (int o = 32; o > 0; o >>= 1) s += __shfl_down(s, o, 64);
    int wave = threadIdx.x >> 6, lane = threadIdx.x & 63;
    if (lane == 0) w[wave] = s;
    __syncthreads();
    if (threadIdx.x == 0) out[0] = (w[0] + w[1] + w[2] + w[3]) * scale;
}

extern "C" void kernel_launch(void* const* d_in, const int* in_sizes, int n_in,
                              void* d_out, int out_size, void* d_ws, size_t ws_size,
                              hipStream_t stream) {
    (void)in_sizes; (void)n_in; (void)out_size; (void)ws_size;
    const float* X   = (const float*)d_in[0];
    const int*   tgt = (const int*)d_in[1];

    uint8_t* Xq     = (uint8_t*)d_ws;                              // 2 MB fp8
    float* sq       = (float*)((char*)d_ws + (size_t)N * KDIM);
    float* partials = sq + N;                                      // GRID floats

    prep_kernel<<<N / 4, 256, 0, stream>>>(X, Xq, sq);
    loss_kernel<<<GRID, 256, 0, stream>>>(Xq, sq, tgt, partials);

    const float scale = (float)(1.0 / ((double)N * ((double)N - 1.0) * 2.0));
    reduce_kernel<<<1, 256, 0, stream>>>(partials, (float*)d_out, GRID, scale);
}

// Round 8
// 107.978 us; speedup vs baseline: 1.4428x; 1.4428x over previous
//
#include <hip/hip_runtime.h>
#include <stdint.h>

#define N      8192
#define KDIM   256
#define BM     128
#define TILES  (N / BM)                    // 64
#define NPAIRS (TILES * (TILES + 1) / 2)   // 2080
#define GRID   1024                        // 4 persistent blocks per CU
#define MARGIN 0.5f
#define SCALE1 0x7f7f7f7f                  // E8M0 1.0 in every byte

typedef float f32x4 __attribute__((ext_vector_type(4)));
typedef int   i32x4 __attribute__((ext_vector_type(4)));
typedef int   i32x8 __attribute__((ext_vector_type(8)));

__device__ __forceinline__ void async_copy16(const void* g, void* l) {
    __builtin_amdgcn_global_load_lds(
        (__attribute__((address_space(1))) void*)(g),
        (__attribute__((address_space(3))) void*)(l),
        16, 0, 0);
}

#if !__has_builtin(__builtin_amdgcn_cvt_pk_fp8_f32)
__device__ __forceinline__ uint32_t f2e4m3(float f) {
    uint32_t u = __float_as_uint(f);
    uint32_t s = (u >> 24) & 0x80u;
    uint32_t au = u & 0x7fffffffu;
    if (au == 0) return s;
    int32_t  exp = (int32_t)(au >> 23) - 127;
    uint32_t man = (au & 0x7fffffu) | 0x800000u;
    uint32_t code;
    if (exp >= -6) {
        code = (uint32_t)((exp + 7) << 3) | ((man >> 20) & 7u);
        uint32_t rem = man & 0xFFFFFu;
        if (rem > 0x80000u || (rem == 0x80000u && (code & 1u))) code++;
    } else {
        int shift = 14 - exp;
        if (shift > 24) return s;
        code = man >> shift;
        uint32_t rem = man & ((1u << shift) - 1u);
        uint32_t h = 1u << (shift - 1);
        if (rem > h || (rem == h && (code & 1u))) code++;
    }
    return s | code;
}
__device__ __forceinline__ uint32_t pack_fp8x4(float4 v) {
    return f2e4m3(v.x) | (f2e4m3(v.y) << 8) | (f2e4m3(v.z) << 16) |
           (f2e4m3(v.w) << 24);
}
#else
__device__ __forceinline__ uint32_t pack_fp8x4(float4 v) {
    int pk = __builtin_amdgcn_cvt_pk_fp8_f32(v.x, v.y, 0, false);
    pk = __builtin_amdgcn_cvt_pk_fp8_f32(v.z, v.w, pk, true);
    return (uint32_t)pk;
}
#endif

// ---------------------------------------------------------------------------
// Prepass: fp32 -> fp8 e4m3, row-major 256 B/row, 16 B granules XOR-swizzled
// by (row&7) within each 128 B half. Exact fp32 row norms.
// ---------------------------------------------------------------------------
__global__ __launch_bounds__(256) void prep_kernel(
        const float* __restrict__ X, uint8_t* __restrict__ Xq,
        float* __restrict__ sq) {
    int row  = blockIdx.x * 4 + (threadIdx.x >> 6);
    int lane = threadIdx.x & 63;

    float4 v = *((const float4*)(X + (size_t)row * KDIM) + lane);
    float ss = v.x * v.x + v.y * v.y + v.z * v.z + v.w * v.w;
    uint32_t pk = pack_fp8x4(v);

    int h   = lane >> 5;
    int g   = (lane >> 2) & 7;
    int pos = g ^ (row & 7);
    *(uint32_t*)(Xq + (size_t)row * 256 + h * 128 + pos * 16 + (lane & 3) * 4) = pk;

    #pragma unroll
    for (int o = 32; o > 0; o >>= 1) ss += __shfl_down(ss, o, 64);
    if (lane == 0) sq[row] = ss;
}

// ---------------------------------------------------------------------------
// Main: 1024 PERSISTENT blocks (4/CU), each looping over 2-3 tile-pairs with
// the round-6 verified per-pair body UNCHANGED (no cross-pair pipelining, no
// register meta caching -> no spills). One extra barrier per pair guards LDS
// reuse. Removes ~1000 CP dispatches and lets resident blocks desynchronize.
// ---------------------------------------------------------------------------
__global__ __launch_bounds__(256, 4) void loss_kernel(
        const uint8_t* __restrict__ Xq, const float* __restrict__ sq,
        const int* __restrict__ tgt, float* __restrict__ partials) {
    __shared__ __align__(16) uint8_t As[BM * 128];   // 16 KB (one K-half)
    __shared__ __align__(16) uint8_t Bs[BM * 128];   // 16 KB
    __shared__ float sqa_s[BM], sqb_s[BM];
    __shared__ int   ta_s[BM],  tb_s[BM];
    __shared__ float wsum[4];

    const int tid  = threadIdx.x;
    const int wave = tid >> 6;
    const int lane = tid & 63;

    const int frow  = lane & 15;
    const int fquad = lane >> 4;
    const int wm  = (wave >> 1) * 64;
    const int wn  = (wave & 1) * 64;
    const int key  = frow & 7;
    const int off0 = ((fquad * 2 + 0) ^ key) * 16;
    const int off1 = ((fquad * 2 + 1) ^ key) * 16;
    const uint8_t* aBp = As + (wm + frow) * 128;
    const uint8_t* bBp = Bs + (wn + frow) * 128;

    const int lrow = lane >> 3;
    const int lb   = (lane & 7) * 16;
    uint8_t* lA = As + wave * 32 * 128;
    uint8_t* lB = Bs + wave * 32 * 128;

    float total = 0.0f;
    bool  first = true;

    for (int p = blockIdx.x; p < NPAIRS; p += GRID) {
        // ---- triangular decode: p -> (bi, bj), bi <= bj ----
        float tf = 2.0f * TILES + 1.0f;
        int bi = (int)((tf - sqrtf(tf * tf - 8.0f * (float)p)) * 0.5f);
        if (bi < 0) bi = 0;
        while (bi > 0 && (bi * TILES - bi * (bi - 1) / 2) > p) --bi;
        while (((bi + 1) * TILES - (bi + 1) * bi / 2) <= p) ++bi;
        const int bj = bi + (p - (bi * TILES - bi * (bi - 1) / 2));

        if (!first) __syncthreads();   // prior pair's LDS reads all done
        first = false;

        if (tid < 128) {
            sqa_s[tid] = sq[bi * BM + tid];
            ta_s[tid]  = tgt[bi * BM + tid];
        } else {
            int r = tid - 128;
            sqb_s[r] = sq[bj * BM + r];
            tb_s[r]  = tgt[bj * BM + r];
        }

        const uint8_t* gA =
            Xq + ((size_t)bi * BM + wave * 32 + lrow) * 256 + lb;
        const uint8_t* gB =
            Xq + ((size_t)bj * BM + wave * 32 + lrow) * 256 + lb;

        f32x4 acc[4][4];
        #pragma unroll
        for (int im = 0; im < 4; ++im)
            #pragma unroll
            for (int in = 0; in < 4; ++in)
                acc[im][in] = (f32x4){0.f, 0.f, 0.f, 0.f};

        #pragma unroll
        for (int h = 0; h < 2; ++h) {
            #pragma unroll
            for (int q = 0; q < 4; ++q) {
                async_copy16(gA + h * 128 + q * 8 * 256, lA + q * 1024);
                async_copy16(gB + h * 128 + q * 8 * 256, lB + q * 1024);
            }
            __syncthreads();

            i32x8 a8[4];
            #pragma unroll
            for (int im = 0; im < 4; ++im) {
                i32x4 al = *(const i32x4*)(aBp + im * 16 * 128 + off0);
                i32x4 ah = *(const i32x4*)(aBp + im * 16 * 128 + off1);
                a8[im] = __builtin_shufflevector(al, ah, 0, 1, 2, 3, 4, 5, 6, 7);
            }
            #pragma unroll
            for (int in = 0; in < 4; ++in) {
                i32x4 bl = *(const i32x4*)(bBp + in * 16 * 128 + off0);
                i32x4 bh = *(const i32x4*)(bBp + in * 16 * 128 + off1);
                i32x8 b8 = __builtin_shufflevector(bl, bh, 0, 1, 2, 3, 4, 5, 6, 7);
                #pragma unroll
                for (int im = 0; im < 4; ++im)
                    acc[im][in] =
                        __builtin_amdgcn_mfma_scale_f32_16x16x128_f8f6f4(
                            a8[im], b8, acc[im][in], 0, 0,
                            0, SCALE1, 0, SCALE1);
            }
            if (h == 0) __syncthreads();   // LDS reuse guard before restaging
        }

        // ---- epilogue: C/D map col=lane&15, row=(lane>>4)*4+reg ----
        float ls = 0.0f;
        if (bi != bj) {
            #pragma unroll
            for (int im = 0; im < 4; ++im)
                #pragma unroll
                for (int in = 0; in < 4; ++in)
                    #pragma unroll
                    for (int r = 0; r < 4; ++r) {
                        int rl = wm + im * 16 + fquad * 4 + r;
                        int cl = wn + in * 16 + frow;
                        float d = fmaf(-2.0f, acc[im][in][r],
                                       sqa_s[rl] + sqb_s[cl]);
                        ls += (ta_s[rl] == tb_s[cl])
                                  ? d : fmaxf(MARGIN - d, 0.0f);
                    }
            total += 2.0f * ls;
        } else {
            #pragma unroll
            for (int im = 0; im < 4; ++im)
                #pragma unroll
                for (int in = 0; in < 4; ++in)
                    #pragma unroll
                    for (int r = 0; r < 4; ++r) {
                        int rl = wm + im * 16 + fquad * 4 + r;
                        int cl = wn + in * 16 + frow;
                        float d = fmaf(-2.0f, acc[im][in][r],
                                       sqa_s[rl] + sqb_s[cl]);
                        float c = (ta_s[rl] == tb_s[cl])
                                      ? d : fmaxf(MARGIN - d, 0.0f);
                        float w = (rl < cl) ? 2.0f : ((rl == cl) ? 1.0f : 0.0f);
                        ls += w * c;
                    }
            total += ls;
        }
    }

    // ---- per-block reduction (once) ----
    #pragma unroll
    for (int o = 32; o > 0; o >>= 1) total += __shfl_down(total, o, 64);
    __syncthreads();                       // last pair's meta reads done
    if (lane == 0) wsum[wave] = total;
    __syncthreads();
    if (tid == 0) partials[blockIdx.x] = wsum[0] + wsum[1] + wsum[2] + wsum[3];
}

// ---------------------------------------------------------------------------
// Final deterministic reduce of GRID partials -> scaled scalar.
// ---------------------------------------------------------------------------
__global__ __launch_bounds__(256) void reduce_kernel(
        const float* __restrict__ partials, float* __restrict__ out,
        int n, float scale) {
    float s = 0.0f;
    for (int i = threadIdx.x; i < n; i += 256) s += partials[i];
    __shared__ float w[4];
    #pragma unroll
    for (int o = 32; o > 0; o >>= 1) s += __shfl_down(s, o, 64);
    int wave = threadIdx.x >> 6, lane = threadIdx.x & 63;
    if (lane == 0) w[wave] = s;
    __syncthreads();
    if (threadIdx.x == 0) out[0] = (w[0] + w[1] + w[2] + w[3]) * scale;
}

extern "C" void kernel_launch(void* const* d_in, const int* in_sizes, int n_in,
                              void* d_out, int out_size, void* d_ws, size_t ws_size,
                              hipStream_t stream) {
    (void)in_sizes; (void)n_in; (void)out_size; (void)ws_size;
    const float* X   = (const float*)d_in[0];
    const int*   tgt = (const int*)d_in[1];

    uint8_t* Xq     = (uint8_t*)d_ws;                              // 2 MB fp8
    float* sq       = (float*)((char*)d_ws + (size_t)N * KDIM);
    float* partials = sq + N;                                      // GRID floats

    prep_kernel<<<N / 4, 256, 0, stream>>>(X, Xq, sq);
    loss_kernel<<<GRID, 256, 0, stream>>>(Xq, sq, tgt, partials);

    const float scale = (float)(1.0 / ((double)N * ((double)N - 1.0) * 2.0));
    reduce_kernel<<<1, 256, 0, stream>>>(partials, (float*)d_out, GRID, scale);
}

// Round 9
// 85.277 us; speedup vs baseline: 1.8268x; 1.2662x over previous
//
#include <hip/hip_runtime.h>
#include <stdint.h>

#define N      8192
#define KDIM   256
#define BT     256                          // super-tile edge
#define TILES2 (N / BT)                     // 32
#define NP2    (TILES2 * (TILES2 + 1) / 2)  // 528
#define MARGIN 0.5f
#define SCALE1 0x7f7f7f7f                   // E8M0 1.0 in every byte

typedef float f32x4 __attribute__((ext_vector_type(4)));
typedef int   i32x4 __attribute__((ext_vector_type(4)));
typedef int   i32x8 __attribute__((ext_vector_type(8)));

__device__ __forceinline__ void async_copy16(const void* g, void* l) {
    __builtin_amdgcn_global_load_lds(
        (__attribute__((address_space(1))) void*)(g),
        (__attribute__((address_space(3))) void*)(l),
        16, 0, 0);
}

#if !__has_builtin(__builtin_amdgcn_cvt_pk_fp8_f32)
__device__ __forceinline__ uint32_t f2e4m3(float f) {
    uint32_t u = __float_as_uint(f);
    uint32_t s = (u >> 24) & 0x80u;
    uint32_t au = u & 0x7fffffffu;
    if (au == 0) return s;
    int32_t  exp = (int32_t)(au >> 23) - 127;
    uint32_t man = (au & 0x7fffffu) | 0x800000u;
    uint32_t code;
    if (exp >= -6) {
        code = (uint32_t)((exp + 7) << 3) | ((man >> 20) & 7u);
        uint32_t rem = man & 0xFFFFFu;
        if (rem > 0x80000u || (rem == 0x80000u && (code & 1u))) code++;
    } else {
        int shift = 14 - exp;
        if (shift > 24) return s;
        code = man >> shift;
        uint32_t rem = man & ((1u << shift) - 1u);
        uint32_t h = 1u << (shift - 1);
        if (rem > h || (rem == h && (code & 1u))) code++;
    }
    return s | code;
}
__device__ __forceinline__ uint32_t pack_fp8x4(float4 v) {
    return f2e4m3(v.x) | (f2e4m3(v.y) << 8) | (f2e4m3(v.z) << 16) |
           (f2e4m3(v.w) << 24);
}
#else
__device__ __forceinline__ uint32_t pack_fp8x4(float4 v) {
    int pk = __builtin_amdgcn_cvt_pk_fp8_f32(v.x, v.y, 0, false);
    pk = __builtin_amdgcn_cvt_pk_fp8_f32(v.z, v.w, pk, true);
    return (uint32_t)pk;
}
#endif

// ---------------------------------------------------------------------------
// Prepass: fp32 -> fp8 e4m3, row-major 256 B/row, 16 B granules XOR-swizzled
// by (row&7) within each 128 B half. Exact fp32 row norms. (Unchanged R6.)
// ---------------------------------------------------------------------------
__global__ __launch_bounds__(256) void prep_kernel(
        const float* __restrict__ X, uint8_t* __restrict__ Xq,
        float* __restrict__ sq) {
    int row  = blockIdx.x * 4 + (threadIdx.x >> 6);
    int lane = threadIdx.x & 63;

    float4 v = *((const float4*)(X + (size_t)row * KDIM) + lane);
    float ss = v.x * v.x + v.y * v.y + v.z * v.z + v.w * v.w;
    uint32_t pk = pack_fp8x4(v);

    int h   = lane >> 5;
    int g   = (lane >> 2) & 7;
    int pos = g ^ (row & 7);
    *(uint32_t*)(Xq + (size_t)row * 256 + h * 128 + pos * 16 + (lane & 3) * 4) = pk;

    #pragma unroll
    for (int o = 32; o > 0; o >>= 1) ss += __shfl_down(ss, o, 64);
    if (lane == 0) sq[row] = ss;
}

// ---------------------------------------------------------------------------
// Main: triangular grid of 256x256 SUPER-tiles; 1024-thread blocks (16 waves
// in a 4x4 grid, each wave the same verified 64x64 quadrant job as R4/R6).
// 4x work per WG: 528 dispatches instead of 2080, staged L2 bytes halved.
// Per-wave inner machinery identical to R6 (MX-scaled fp8, BK=128, 3 barriers).
// ---------------------------------------------------------------------------
__global__ __launch_bounds__(1024, 4) void loss_kernel(
        const uint8_t* __restrict__ Xq, const float* __restrict__ sq,
        const int* __restrict__ tgt, float* __restrict__ partials) {
    // ---- triangular decode: p -> (BI, BJ), BI <= BJ over 32 tiles ----
    const int p = blockIdx.x;
    float tf = 2.0f * TILES2 + 1.0f;
    int BI = (int)((tf - sqrtf(tf * tf - 8.0f * (float)p)) * 0.5f);
    if (BI < 0) BI = 0;
    while (BI > 0 && (BI * TILES2 - BI * (BI - 1) / 2) > p) --BI;
    while (((BI + 1) * TILES2 - (BI + 1) * BI / 2) <= p) ++BI;
    const int BJ = BI + (p - (BI * TILES2 - BI * (BI - 1) / 2));

    __shared__ __align__(16) uint8_t As[BT * 128];   // 32 KB (one K-half)
    __shared__ __align__(16) uint8_t Bs[BT * 128];   // 32 KB
    __shared__ float sqa_s[BT], sqb_s[BT];
    __shared__ int   ta_s[BT],  tb_s[BT];
    __shared__ float wsum[16];

    const int tid  = threadIdx.x;
    const int wave = tid >> 6;     // 0..15
    const int lane = tid & 63;

    if (tid < 256) {
        sqa_s[tid] = sq[BI * BT + tid];
        ta_s[tid]  = tgt[BI * BT + tid];
    } else if (tid < 512) {
        int r = tid - 256;
        sqb_s[r] = sq[BJ * BT + r];
        tb_s[r]  = tgt[BJ * BT + r];
    }

    // staging: wave w stages rows [w*16, w*16+16) of both tiles
    const int lrow = lane >> 3;            // 0..7
    const int lb   = (lane & 7) * 16;
    const uint8_t* gA =
        Xq + ((size_t)BI * BT + wave * 16 + lrow) * 256 + lb;
    const uint8_t* gB =
        Xq + ((size_t)BJ * BT + wave * 16 + lrow) * 256 + lb;
    uint8_t* lA = As + wave * 16 * 128;
    uint8_t* lB = Bs + wave * 16 * 128;

    // compute mapping: wave (wr,wc) owns 64x64 quadrant
    const int wr = wave >> 2;
    const int wc = wave & 3;
    const int frow  = lane & 15;
    const int fquad = lane >> 4;
    const int wm = wr * 64;
    const int wn = wc * 64;
    const int key  = frow & 7;
    const int off0 = ((fquad * 2 + 0) ^ key) * 16;
    const int off1 = ((fquad * 2 + 1) ^ key) * 16;
    const uint8_t* aBp = As + (wm + frow) * 128;
    const uint8_t* bBp = Bs + (wn + frow) * 128;

    f32x4 acc[4][4];
    #pragma unroll
    for (int im = 0; im < 4; ++im)
        #pragma unroll
        for (int in = 0; in < 4; ++in)
            acc[im][in] = (f32x4){0.f, 0.f, 0.f, 0.f};

    #pragma unroll
    for (int h = 0; h < 2; ++h) {
        // stage K-half h: per wave 2 issues x (A,B) of 8 rows x 128 B
        #pragma unroll
        for (int i = 0; i < 2; ++i) {
            async_copy16(gA + h * 128 + i * 8 * 256, lA + i * 1024);
            async_copy16(gB + h * 128 + i * 8 * 256, lB + i * 1024);
        }
        __syncthreads();

        i32x8 a8[4];
        #pragma unroll
        for (int im = 0; im < 4; ++im) {
            i32x4 al = *(const i32x4*)(aBp + im * 16 * 128 + off0);
            i32x4 ah = *(const i32x4*)(aBp + im * 16 * 128 + off1);
            a8[im] = __builtin_shufflevector(al, ah, 0, 1, 2, 3, 4, 5, 6, 7);
        }
        #pragma unroll
        for (int in = 0; in < 4; ++in) {
            i32x4 bl = *(const i32x4*)(bBp + in * 16 * 128 + off0);
            i32x4 bh = *(const i32x4*)(bBp + in * 16 * 128 + off1);
            i32x8 b8 = __builtin_shufflevector(bl, bh, 0, 1, 2, 3, 4, 5, 6, 7);
            #pragma unroll
            for (int im = 0; im < 4; ++im)
                acc[im][in] = __builtin_amdgcn_mfma_scale_f32_16x16x128_f8f6f4(
                    a8[im], b8, acc[im][in], 0, 0, 0, SCALE1, 0, SCALE1);
        }
        if (h == 0) __syncthreads();   // LDS reuse guard before restaging
    }

    // ---- epilogue: C/D map col=lane&15, row=(lane>>4)*4+reg ----
    float ls = 0.0f;
    if (BI != BJ) {
        #pragma unroll
        for (int im = 0; im < 4; ++im)
            #pragma unroll
            for (int in = 0; in < 4; ++in)
                #pragma unroll
                for (int r = 0; r < 4; ++r) {
                    int rl = wm + im * 16 + fquad * 4 + r;
                    int cl = wn + in * 16 + frow;
                    float d = fmaf(-2.0f, acc[im][in][r],
                                   sqa_s[rl] + sqb_s[cl]);
                    ls += (ta_s[rl] == tb_s[cl]) ? d : fmaxf(MARGIN - d, 0.0f);
                }
        ls *= 2.0f;   // (i,j) and (j,i)
    } else {
        #pragma unroll
        for (int im = 0; im < 4; ++im)
            #pragma unroll
            for (int in = 0; in < 4; ++in)
                #pragma unroll
                for (int r = 0; r < 4; ++r) {
                    int rl = wm + im * 16 + fquad * 4 + r;
                    int cl = wn + in * 16 + frow;
                    float d = fmaf(-2.0f, acc[im][in][r],
                                   sqa_s[rl] + sqb_s[cl]);
                    float c = (ta_s[rl] == tb_s[cl]) ? d
                                                     : fmaxf(MARGIN - d, 0.0f);
                    float w = (rl < cl) ? 2.0f : ((rl == cl) ? 1.0f : 0.0f);
                    ls += w * c;
                }
    }

    #pragma unroll
    for (int o = 32; o > 0; o >>= 1) ls += __shfl_down(ls, o, 64);
    if (lane == 0) wsum[wave] = ls;
    __syncthreads();
    if (tid == 0) {
        float s = 0.0f;
        #pragma unroll
        for (int w = 0; w < 16; ++w) s += wsum[w];
        partials[p] = s;
    }
}

// ---------------------------------------------------------------------------
// Final deterministic reduce of NP2 partials -> scaled scalar.
// ---------------------------------------------------------------------------
__global__ __launch_bounds__(256) void reduce_kernel(
        const float* __restrict__ partials, float* __restrict__ out,
        int n, float scale) {
    float s = 0.0f;
    for (int i = threadIdx.x; i < n; i += 256) s += partials[i];
    __shared__ float w[4];
    #pragma unroll
    for (int o = 32; o > 0; o >>= 1) s += __shfl_down(s, o, 64);
    int wave = threadIdx.x >> 6, lane = threadIdx.x & 63;
    if (lane == 0) w[wave] = s;
    __syncthreads();
    if (threadIdx.x == 0) out[0] = (w[0] + w[1] + w[2] + w[3]) * scale;
}

extern "C" void kernel_launch(void* const* d_in, const int* in_sizes, int n_in,
                              void* d_out, int out_size, void* d_ws, size_t ws_size,
                              hipStream_t stream) {
    (void)in_sizes; (void)n_in; (void)out_size; (void)ws_size;
    const float* X   = (const float*)d_in[0];
    const int*   tgt = (const int*)d_in[1];

    uint8_t* Xq     = (uint8_t*)d_ws;                              // 2 MB fp8
    float* sq       = (float*)((char*)d_ws + (size_t)N * KDIM);
    float* partials = sq + N;                                      // NP2 floats

    prep_kernel<<<N / 4, 256, 0, stream>>>(X, Xq, sq);
    loss_kernel<<<NP2, 1024, 0, stream>>>(Xq, sq, tgt, partials);

    const float scale = (float)(1.0 / ((double)N * ((double)N - 1.0) * 2.0));
    reduce_kernel<<<1, 256, 0, stream>>>(partials, (float*)d_out, NP2, scale);
}